// Round 2
// baseline (1024.864 us; speedup 1.0000x reference)
//
#include <hip/hip_runtime.h>

#define NN     4096
#define NFEAT  512
#define NHID   64
#define NHEADS 8
#define NS     64
#define NEDGE  131072
#define NHH    512
#define MASKW  (NN/32)   // 128 words per row

typedef _Float16 f16;
typedef _Float16 f16x4 __attribute__((ext_vector_type(4)));
typedef _Float16 f16x8 __attribute__((ext_vector_type(8)));
typedef float    f32x4 __attribute__((ext_vector_type(4)));

// ---------------- prep kernels ----------------

// pack adj (int32 0/1) into bitmask: bit b of word w = adj[w*32+b] > 0
__global__ __launch_bounds__(256) void k_pack_mask(const int* __restrict__ adj,
                                                   unsigned* __restrict__ mb) {
  int w = blockIdx.x * 256 + threadIdx.x;
  const int4* p = (const int4*)(adj + (size_t)w * 32);
  unsigned m = 0;
#pragma unroll
  for (int c = 0; c < 8; c++) {
    int4 v = p[c];
    m |= (v.x > 0 ? 1u : 0u) << (4*c)     | (v.y > 0 ? 1u : 0u) << (4*c + 1)
       | (v.z > 0 ? 1u : 0u) << (4*c + 2) | (v.w > 0 ? 1u : 0u) << (4*c + 3);
  }
  mb[w] = m;
}

__global__ __launch_bounds__(256) void k_cast(const float* __restrict__ in,
                                              f16* __restrict__ out, int n) {
  int i = blockIdx.x * 256 + threadIdx.x;
  if (i < n) out[i] = (f16)in[i];
}

// WcatT[n][k] = W_heads[n>>6][k][n&63]  (n = head*64+f), out [512][512] f16
__global__ __launch_bounds__(256) void k_wcatT(const float* __restrict__ W,
                                               f16* __restrict__ out) {
  int idx = blockIdx.x * 256 + threadIdx.x;
  int n = idx >> 9, k = idx & 511;
  out[idx] = (f16)W[(n >> 6) * (NFEAT * NHID) + k * NHID + (n & 63)];
}

// WoutT[n][k] = W_out[k][n]
__global__ __launch_bounds__(256) void k_transT(const float* __restrict__ W,
                                                f16* __restrict__ out) {
  int idx = blockIdx.x * 256 + threadIdx.x;
  int n = idx >> 9, k = idx & 511;
  out[idx] = (f16)W[k * NHH + n];
}

// hcat[i][512+c] = s[i][c]   (hcat leading dim 576)
__global__ __launch_bounds__(256) void k_s_hcat(const float* __restrict__ s,
                                                f16* __restrict__ hcat) {
  int idx = blockIdx.x * 256 + threadIdx.x;
  int i = idx >> 6, c = idx & 63;
  hcat[(size_t)i * 576 + 512 + c] = (f16)s[idx];
}

// ---------------- GEMM: C = A[M][lda] @ BT[n][k]^T ----------------
// MODE 0: store C^T as f16 into outT[n][ldo]   (ldo = M total)
// MODE 1: store C as f32 into out[m][ldo] (+ bias[n] if bias)
// block = 256 (4 waves); tile 64x64; wave w -> rows bx*64+w*16; K step 32
template<int MODE>
__global__ __launch_bounds__(256) void k_gemm(const f16* __restrict__ A, int lda,
                                              const f16* __restrict__ BT, int ldbt,
                                              void* __restrict__ outp, int ldo,
                                              const float* __restrict__ bias, int K) {
  int w = threadIdx.x >> 6, l = threadIdx.x & 63;
  int g = l >> 4, ln = l & 15;
  int row  = blockIdx.x * 64 + w * 16 + ln;
  int colb = blockIdx.y * 64;
  const f16* ap = A + (size_t)row * lda + 4 * g;
  f32x4 acc[4];
#pragma unroll
  for (int nf = 0; nf < 4; nf++) acc[nf] = (f32x4){0.f, 0.f, 0.f, 0.f};
  for (int k0 = 0; k0 < K; k0 += 32) {
    f16x4 alo = *(const f16x4*)(ap + k0);
    f16x4 ahi = *(const f16x4*)(ap + k0 + 16);
    f16x8 af = {alo[0], alo[1], alo[2], alo[3], ahi[0], ahi[1], ahi[2], ahi[3]};
#pragma unroll
    for (int nf = 0; nf < 4; nf++) {
      const f16* bp = BT + (size_t)(colb + nf * 16 + ln) * ldbt + k0 + 4 * g;
      f16x4 blo = *(const f16x4*)(bp);
      f16x4 bhi = *(const f16x4*)(bp + 16);
      f16x8 bf = {blo[0], blo[1], blo[2], blo[3], bhi[0], bhi[1], bhi[2], bhi[3]};
      acc[nf] = __builtin_amdgcn_mfma_f32_16x16x32_f16(af, bf, acc[nf], 0, 0, 0);
    }
  }
  int m0 = blockIdx.x * 64 + w * 16 + 4 * g;   // C/D: col=lane&15, row=4*(l>>4)+r (m89)
#pragma unroll
  for (int nf = 0; nf < 4; nf++) {
    int n = colb + nf * 16 + ln;
    if (MODE == 0) {
      f16* oT = (f16*)outp;
      f16x4 v = {(f16)acc[nf][0], (f16)acc[nf][1], (f16)acc[nf][2], (f16)acc[nf][3]};
      *(f16x4*)(oT + (size_t)n * ldo + m0) = v;
    } else {
      float* o = (float*)outp;
      float b = bias ? bias[n] : 0.f;
#pragma unroll
      for (int r = 0; r < 4; r++) o[(size_t)(m0 + r) * ldo + n] = acc[nf][r] + b;
    }
  }
}

// src[h][i] = sum_f WhT[h*fo+f][i]*a[h][f];  dst uses a[h][fo+f]
__global__ __launch_bounds__(256) void k_srcdst(const f16* __restrict__ WhT,
                                                const float* __restrict__ a,
                                                float* __restrict__ sv,
                                                float* __restrict__ dv, int fo) {
  int h = blockIdx.y;
  int i = blockIdx.x * 256 + threadIdx.x;
  const f16* wp = WhT + (size_t)h * fo * NN + i;
  const float* ap = a + h * 2 * fo;
  float sacc = 0.f, dacc = 0.f;
  for (int f = 0; f < fo; f++) {
    float v = (float)wp[(size_t)f * NN];
    sacc = fmaf(v, ap[f], sacc);
    dacc = fmaf(v, ap[fo + f], dacc);
  }
  sv[h * NN + i] = sacc;
  dv[h * NN + i] = dacc;
}

// ---------------- fused masked GAT attention (flash-style) ----------------
// block = 256 (4 waves), 64 rows/block, 64 cols/block (NF=4 x 16).
// grid.y: layer1 -> head (sstride=NN); layer2 -> col-block (sstride=0).
// Scores e=leaky(src_i+dst_j); w=exp(e) (no max sub needed, |e|<~6); masked->0.
// A-fragment built in-register with the same K-permutation as B loads.
template<bool ELU>
__global__ __launch_bounds__(256) void k_attn(const f16* __restrict__ WhT,
                                              const float* __restrict__ sv,
                                              const float* __restrict__ dv, int sstride,
                                              const unsigned* __restrict__ mb,
                                              f16* __restrict__ hout, int ldo) {
  int w = threadIdx.x >> 6, l = threadIdx.x & 63;
  int g = l >> 4, ln = l & 15;
  int i = blockIdx.x * 64 + w * 16 + ln;        // this lane's A-frag row
  int colbase = blockIdx.y * 64;
  float si = sv[blockIdx.y * sstride + i];
  const float* dp = dv + blockIdx.y * sstride;
  const unsigned* mrow = mb + (size_t)i * MASKW;
  f32x4 acc[4];
#pragma unroll
  for (int nf = 0; nf < 4; nf++) acc[nf] = (f32x4){0.f, 0.f, 0.f, 0.f};
  float rsum = 0.f;
  for (int j0 = 0; j0 < NN; j0 += 32) {
    unsigned m32 = mrow[j0 >> 5];
    f32x4 dlo = *(const f32x4*)(dp + j0 + 4 * g);
    f32x4 dhi = *(const f32x4*)(dp + j0 + 16 + 4 * g);
    f16x8 af;
#pragma unroll
    for (int d = 0; d < 4; d++) {
      float e = si + dlo[d];
      e = fmaxf(e, 0.2f * e);                    // LeakyReLU(0.2)
      float we = __expf(e);
      we = ((m32 >> (4 * g + d)) & 1u) ? we : 0.f;
      rsum += we;
      af[d] = (f16)we;
      float e2 = si + dhi[d];
      e2 = fmaxf(e2, 0.2f * e2);
      float we2 = __expf(e2);
      we2 = ((m32 >> (16 + 4 * g + d)) & 1u) ? we2 : 0.f;
      rsum += we2;
      af[4 + d] = (f16)we2;
    }
#pragma unroll
    for (int nf = 0; nf < 4; nf++) {
      const f16* bp = WhT + (size_t)(colbase + nf * 16 + ln) * NN + j0 + 4 * g;
      f16x4 blo = *(const f16x4*)bp;
      f16x4 bhi = *(const f16x4*)(bp + 16);
      f16x8 bf = {blo[0], blo[1], blo[2], blo[3], bhi[0], bhi[1], bhi[2], bhi[3]};
      acc[nf] = __builtin_amdgcn_mfma_f32_16x16x32_f16(af, bf, acc[nf], 0, 0, 0);
    }
  }
  // full row sums: 4 lanegroups hold disjoint j-partials of the same row (l&15)
  rsum += __shfl_xor(rsum, 16, 64);
  rsum += __shfl_xor(rsum, 32, 64);
#pragma unroll
  for (int r = 0; r < 4; r++) {
    float rs = __shfl(rsum, 4 * g + r, 64);      // rowsum for C-row 4g+r
    float inv = 1.f / rs;
    int orow = blockIdx.x * 64 + w * 16 + 4 * g + r;
#pragma unroll
    for (int nf = 0; nf < 4; nf++) {
      float v = acc[nf][r] * inv;
      if (ELU) v = v > 0.f ? v : (__expf(v) - 1.f);
      hout[(size_t)orow * ldo + colbase + nf * 16 + ln] = (f16)v;
    }
  }
}

// ---------------- edge MLP: out[e] = dot(relu(P[src]+Q[dst]), w2) + b2 ----------------
__global__ __launch_bounds__(256) void k_edge(const float* __restrict__ P,
                                              const float* __restrict__ Q,
                                              const int* __restrict__ ids,
                                              const float* __restrict__ w2,
                                              const float* __restrict__ b2,
                                              float* __restrict__ out) {
  int t = blockIdx.x * 256 + threadIdx.x;
  int e = t >> 6, l = t & 63;                   // one wave per edge
  int sn = ids[2 * e], dn = ids[2 * e + 1];
  const float* p  = P  + (size_t)sn * NHH + l * 8;
  const float* q  = Q  + (size_t)dn * NHH + l * 8;
  const float* wv = w2 + l * 8;
  float acc = 0.f;
#pragma unroll
  for (int c = 0; c < 2; c++) {
    f32x4 pv = *(const f32x4*)(p + 4 * c);
    f32x4 qv = *(const f32x4*)(q + 4 * c);
    f32x4 ww = *(const f32x4*)(wv + 4 * c);
#pragma unroll
    for (int u = 0; u < 4; u++) acc = fmaf(fmaxf(pv[u] + qv[u], 0.f), ww[u], acc);
  }
#pragma unroll
  for (int m = 1; m < 64; m <<= 1) acc += __shfl_xor(acc, m, 64);
  if (l == 0) out[e] = acc + b2[0];
}

// ---------------- launch ----------------
extern "C" void kernel_launch(void* const* d_in, const int* in_sizes, int n_in,
                              void* d_out, int out_size, void* d_ws, size_t ws_size,
                              hipStream_t stream) {
  const float* s   = (const float*)d_in[0];
  const float* x   = (const float*)d_in[1];
  const int*   adj = (const int*)d_in[2];
  const int*   ids = (const int*)d_in[3];
  const float* Whd = (const float*)d_in[4];
  const float* ah  = (const float*)d_in[5];
  const float* Wo  = (const float*)d_in[6];
  const float* ao  = (const float*)d_in[7];
  const float* W1  = (const float*)d_in[8];
  const float* b1  = (const float*)d_in[9];
  const float* W2  = (const float*)d_in[10];
  const float* b2  = (const float*)d_in[11];
  float* out = (float*)d_out;

  char* ws = (char*)d_ws;
  size_t off = 0;
  auto alloc = [&](size_t b) { char* p = ws + off; off += (b + 255) & ~(size_t)255; return p; };
  unsigned* mb  = (unsigned*)alloc((size_t)NN * MASKW * 4);   // 2 MB
  f16* xh       = (f16*)alloc((size_t)NN * NFEAT * 2);        // 4 MB
  f16* WcatT    = (f16*)alloc((size_t)NHH * NFEAT * 2);
  f16* WoutT    = (f16*)alloc((size_t)NHH * NHH * 2);
  f16* W1h      = (f16*)alloc((size_t)NHH * 1152 * 2);
  f16* WhT1     = (f16*)alloc((size_t)NHH * NN * 2);          // 4 MB
  f16* h1       = (f16*)alloc((size_t)NN * NHH * 2);          // 4 MB
  f16* WhT2     = (f16*)alloc((size_t)NHH * NN * 2);          // 4 MB
  f16* hcat     = (f16*)alloc((size_t)NN * 576 * 2);          // 4.5 MB
  float* sv1    = (float*)alloc((size_t)NHEADS * NN * 4);
  float* dv1    = (float*)alloc((size_t)NHEADS * NN * 4);
  float* sv2    = (float*)alloc((size_t)NN * 4);
  float* dv2    = (float*)alloc((size_t)NN * 4);
  float* Pb     = (float*)alloc((size_t)NN * NHH * 4);        // 8 MB
  float* Qb     = (float*)alloc((size_t)NN * NHH * 4);        // 8 MB

  k_pack_mask<<<NN * MASKW / 256, 256, 0, stream>>>(adj, mb);
  k_cast<<<NN * NFEAT / 256, 256, 0, stream>>>(x, xh, NN * NFEAT);
  k_wcatT<<<NHH * NFEAT / 256, 256, 0, stream>>>(Whd, WcatT);
  k_transT<<<NHH * NHH / 256, 256, 0, stream>>>(Wo, WoutT);
  k_cast<<<NHH * 1152 / 256, 256, 0, stream>>>(W1, W1h, NHH * 1152);
  k_s_hcat<<<NN * NS / 256, 256, 0, stream>>>(s, hcat);

  // layer 1: WhT1 = (x @ Wcat)^T ; per-head src/dst ; fused attention -> h1
  k_gemm<0><<<dim3(64, 8), 256, 0, stream>>>(xh, NFEAT, WcatT, NFEAT, (void*)WhT1, NN,
                                             (const float*)nullptr, NFEAT);
  k_srcdst<<<dim3(16, 8), 256, 0, stream>>>(WhT1, ah, sv1, dv1, NHID);
  k_attn<true><<<dim3(64, 8), 256, 0, stream>>>(WhT1, sv1, dv1, NN, mb, h1, NHH);

  // layer 2 (out_att): WhT2 = (h1 @ W_out)^T ; attention (no ELU) -> hcat[:, :512]
  k_gemm<0><<<dim3(64, 8), 256, 0, stream>>>(h1, NHH, WoutT, NHH, (void*)WhT2, NN,
                                             (const float*)nullptr, NHH);
  k_srcdst<<<dim3(16, 1), 256, 0, stream>>>(WhT2, ao, sv2, dv2, NHH);
  k_attn<false><<<dim3(64, 8), 256, 0, stream>>>(WhT2, sv2, dv2, 0, mb, hcat, 576);

  // edge MLP restructure: P = hcat@W1[:, :576]^T + b1 ; Q = hcat@W1[:, 576:]^T
  k_gemm<1><<<dim3(64, 8), 256, 0, stream>>>(hcat, 576, W1h, 1152, (void*)Pb, NHH, b1, 576);
  k_gemm<1><<<dim3(64, 8), 256, 0, stream>>>(hcat, 576, W1h + 576, 1152, (void*)Qb, NHH,
                                             (const float*)nullptr, 576);
  k_edge<<<NEDGE / 4, 256, 0, stream>>>(Pb, Qb, ids, W2, b2, out);
}

// Round 8
// 762.249 us; speedup vs baseline: 1.3445x; 1.3445x over previous
//
#include <hip/hip_runtime.h>

#define NN     4096
#define NFEAT  512
#define NHID   64
#define NHEADS 8
#define NS     64
#define NEDGE  131072
#define NHH    512
#define MASKW  (NN/32)   // 128 words per row
#define JS     4         // j-split factor for attention

typedef _Float16 f16;
typedef _Float16 f16x4 __attribute__((ext_vector_type(4)));
typedef _Float16 f16x8 __attribute__((ext_vector_type(8)));
typedef float    f32x4 __attribute__((ext_vector_type(4)));

// ---------------- prep kernels ----------------

// pack adj (int32 0/1) into bitmask: bit b of word w = adj[w*32+b] > 0
__global__ __launch_bounds__(256) void k_pack_mask(const int* __restrict__ adj,
                                                   unsigned* __restrict__ mb) {
  int w = blockIdx.x * 256 + threadIdx.x;
  const int4* p = (const int4*)(adj + (size_t)w * 32);
  unsigned m = 0;
#pragma unroll
  for (int c = 0; c < 8; c++) {
    int4 v = p[c];
    m |= (v.x > 0 ? 1u : 0u) << (4*c)     | (v.y > 0 ? 1u : 0u) << (4*c + 1)
       | (v.z > 0 ? 1u : 0u) << (4*c + 2) | (v.w > 0 ? 1u : 0u) << (4*c + 3);
  }
  mb[w] = m;
}

__global__ __launch_bounds__(256) void k_cast(const float* __restrict__ in,
                                              f16* __restrict__ out, int n) {
  int i = blockIdx.x * 256 + threadIdx.x;
  if (i < n) out[i] = (f16)in[i];
}

// WcatT[n][k] = W_heads[n>>6][k][n&63]  (n = head*64+f), out [512][512] f16
__global__ __launch_bounds__(256) void k_wcatT(const float* __restrict__ W,
                                               f16* __restrict__ out) {
  int idx = blockIdx.x * 256 + threadIdx.x;
  int n = idx >> 9, k = idx & 511;
  out[idx] = (f16)W[(n >> 6) * (NFEAT * NHID) + k * NHID + (n & 63)];
}

// WoutT[n][k] = W_out[k][n]
__global__ __launch_bounds__(256) void k_transT(const float* __restrict__ W,
                                                f16* __restrict__ out) {
  int idx = blockIdx.x * 256 + threadIdx.x;
  int n = idx >> 9, k = idx & 511;
  out[idx] = (f16)W[k * NHH + n];
}

// hcat[i][512+c] = s[i][c]   (hcat leading dim 576)
__global__ __launch_bounds__(256) void k_s_hcat(const float* __restrict__ s,
                                                f16* __restrict__ hcat) {
  int idx = blockIdx.x * 256 + threadIdx.x;
  int i = idx >> 6, c = idx & 63;
  hcat[(size_t)i * 576 + 512 + c] = (f16)s[idx];
}

// ---------------- GEMM: C = A[M][lda] @ BT[n][k]^T ----------------
// MODE 0: store C^T as f16 into outT[n][ldo]   (ldo = M total)
// MODE 1: store C as f32 into out[m][ldo] (+ bias[n] if bias)
// Contiguous-8 K-permutation: lane group g holds k = 8g..8g+7 (one 16B load
// per fragment). Valid since A and B share the permutation (dot is invariant).
template<int MODE>
__global__ __launch_bounds__(256) void k_gemm(const f16* __restrict__ A, int lda,
                                              const f16* __restrict__ BT, int ldbt,
                                              void* __restrict__ outp, int ldo,
                                              const float* __restrict__ bias, int K) {
  int w = threadIdx.x >> 6, l = threadIdx.x & 63;
  int g = l >> 4, ln = l & 15;
  int row  = blockIdx.x * 64 + w * 16 + ln;
  int colb = blockIdx.y * 64;
  const f16* ap = A + (size_t)row * lda + 8 * g;
  f32x4 acc[4];
#pragma unroll
  for (int nf = 0; nf < 4; nf++) acc[nf] = (f32x4){0.f, 0.f, 0.f, 0.f};
  for (int k0 = 0; k0 < K; k0 += 32) {
    f16x8 af = *(const f16x8*)(ap + k0);
#pragma unroll
    for (int nf = 0; nf < 4; nf++) {
      f16x8 bf = *(const f16x8*)(BT + (size_t)(colb + nf * 16 + ln) * ldbt + k0 + 8 * g);
      acc[nf] = __builtin_amdgcn_mfma_f32_16x16x32_f16(af, bf, acc[nf], 0, 0, 0);
    }
  }
  int m0 = blockIdx.x * 64 + w * 16 + 4 * g;   // C/D: col=lane&15, row=4*(l>>4)+r (m89)
#pragma unroll
  for (int nf = 0; nf < 4; nf++) {
    int n = colb + nf * 16 + ln;
    if (MODE == 0) {
      f16* oT = (f16*)outp;
      f16x4 v = {(f16)acc[nf][0], (f16)acc[nf][1], (f16)acc[nf][2], (f16)acc[nf][3]};
      *(f16x4*)(oT + (size_t)n * ldo + m0) = v;
    } else {
      float* o = (float*)outp;
      float b = bias ? bias[n] : 0.f;
#pragma unroll
      for (int r = 0; r < 4; r++) o[(size_t)(m0 + r) * ldo + n] = acc[nf][r] + b;
    }
  }
}

// src[h][i] = sum_f WhT[h*fo+f][i]*a[h][f];  dst uses a[h][fo+f]
__global__ __launch_bounds__(256) void k_srcdst(const f16* __restrict__ WhT,
                                                const float* __restrict__ a,
                                                float* __restrict__ sv,
                                                float* __restrict__ dv, int fo) {
  int h = blockIdx.y;
  int i = blockIdx.x * 256 + threadIdx.x;
  const f16* wp = WhT + (size_t)h * fo * NN + i;
  const float* ap = a + h * 2 * fo;
  float sacc = 0.f, dacc = 0.f;
  for (int f = 0; f < fo; f++) {
    float v = (float)wp[(size_t)f * NN];
    sacc = fmaf(v, ap[f], sacc);
    dacc = fmaf(v, ap[fo + f], dacc);
  }
  sv[h * NN + i] = sacc;
  dv[h * NN + i] = dacc;
}

// ---------------- fused masked GAT attention (flash-style, j-split) ----------------
// grid (rowblocks=64, colblocks=8, JS). Block: 64 rows x 64 cols, j-range NN/JS.
// exp(e) needs no max-sub (|e|<~6) -> partial PV/rsum are linearly combinable.
// Writes f32 partials; k_combine normalizes. Contiguous-8 K-permutation.
__global__ __launch_bounds__(256) void k_attn(const f16* __restrict__ WhT,
                                              const float* __restrict__ sv,
                                              const float* __restrict__ dv, int sstride,
                                              const unsigned* __restrict__ mb,
                                              float* __restrict__ pp,
                                              float* __restrict__ prs) {
  int w = threadIdx.x >> 6, l = threadIdx.x & 63;
  int g = l >> 4, ln = l & 15;
  int i = blockIdx.x * 64 + w * 16 + ln;        // this lane's A-frag row
  int colbase = blockIdx.y * 64;
  int jz = blockIdx.z;
  float si = sv[blockIdx.y * sstride + i];
  const float* dp = dv + blockIdx.y * sstride;
  const unsigned* mrow = mb + (size_t)i * MASKW;
  f32x4 acc[4];
#pragma unroll
  for (int nf = 0; nf < 4; nf++) acc[nf] = (f32x4){0.f, 0.f, 0.f, 0.f};
  float rsum = 0.f;
  for (int j0 = jz * (NN / JS); j0 < (jz + 1) * (NN / JS); j0 += 32) {
    unsigned m32 = mrow[j0 >> 5];
    f32x4 dlo = *(const f32x4*)(dp + j0 + 8 * g);
    f32x4 dhi = *(const f32x4*)(dp + j0 + 8 * g + 4);
    f16x8 af;
#pragma unroll
    for (int d = 0; d < 4; d++) {
      float e = si + dlo[d];
      e = fmaxf(e, 0.2f * e);                    // LeakyReLU(0.2)
      float we = __expf(e);
      we = ((m32 >> (8 * g + d)) & 1u) ? we : 0.f;
      rsum += we;
      af[d] = (f16)we;
      float e2 = si + dhi[d];
      e2 = fmaxf(e2, 0.2f * e2);
      float we2 = __expf(e2);
      we2 = ((m32 >> (8 * g + 4 + d)) & 1u) ? we2 : 0.f;
      rsum += we2;
      af[4 + d] = (f16)we2;
    }
#pragma unroll
    for (int nf = 0; nf < 4; nf++) {
      f16x8 bf = *(const f16x8*)(WhT + (size_t)(colbase + nf * 16 + ln) * NN + j0 + 8 * g);
      acc[nf] = __builtin_amdgcn_mfma_f32_16x16x32_f16(af, bf, acc[nf], 0, 0, 0);
    }
  }
  // full row sums over this j-range: 4 lanegroups hold disjoint partials of row (l&15)
  rsum += __shfl_xor(rsum, 16, 64);
  rsum += __shfl_xor(rsum, 32, 64);
  if (l < 16)
    prs[(size_t)jz * 8 * NN + blockIdx.y * NN + blockIdx.x * 64 + w * 16 + l] = rsum;
  float* o = pp + (size_t)jz * NN * NHH;
  int m0 = blockIdx.x * 64 + w * 16 + 4 * g;
#pragma unroll
  for (int nf = 0; nf < 4; nf++)
#pragma unroll
    for (int r = 0; r < 4; r++)
      o[(size_t)(m0 + r) * NHH + colbase + nf * 16 + ln] = acc[nf][r];
}

// combine j-split partials: out[i][c] = act( sum_jz pp / sum_jz prs )
template<bool ELU>
__global__ __launch_bounds__(256) void k_combine(const float* __restrict__ pp,
                                                 const float* __restrict__ prs,
                                                 f16* __restrict__ outp, int ldo) {
  int idx = blockIdx.x * 256 + threadIdx.x;       // over NN*NHH
  int i = idx >> 9, c = idx & 511;
  float s = 0.f, rs = 0.f;
#pragma unroll
  for (int jz = 0; jz < JS; jz++) {
    s  += pp[(size_t)jz * NN * NHH + idx];
    rs += prs[(size_t)jz * 8 * NN + (size_t)(c >> 6) * NN + i];
  }
  float v = s / rs;
  if (ELU) v = v > 0.f ? v : (__expf(v) - 1.f);
  outp[(size_t)i * ldo + c] = (f16)v;
}

// ---------------- edge MLP: out[e] = dot(relu(P[src]+Q[dst]), w2) + b2 ----------------
__global__ __launch_bounds__(256) void k_edge(const float* __restrict__ P,
                                              const float* __restrict__ Q,
                                              const int* __restrict__ ids,
                                              const float* __restrict__ w2,
                                              const float* __restrict__ b2,
                                              float* __restrict__ out) {
  int t = blockIdx.x * 256 + threadIdx.x;
  int e = t >> 6, l = t & 63;                   // one wave per edge
  int sn = ids[2 * e], dn = ids[2 * e + 1];
  const float* p  = P  + (size_t)sn * NHH + l * 8;
  const float* q  = Q  + (size_t)dn * NHH + l * 8;
  const float* wv = w2 + l * 8;
  float acc = 0.f;
#pragma unroll
  for (int c = 0; c < 2; c++) {
    f32x4 pv = *(const f32x4*)(p + 4 * c);
    f32x4 qv = *(const f32x4*)(q + 4 * c);
    f32x4 ww = *(const f32x4*)(wv + 4 * c);
#pragma unroll
    for (int u = 0; u < 4; u++) acc = fmaf(fmaxf(pv[u] + qv[u], 0.f), ww[u], acc);
  }
#pragma unroll
  for (int m = 1; m < 64; m <<= 1) acc += __shfl_xor(acc, m, 64);
  if (l == 0) out[e] = acc + b2[0];
}

// ---------------- launch ----------------
extern "C" void kernel_launch(void* const* d_in, const int* in_sizes, int n_in,
                              void* d_out, int out_size, void* d_ws, size_t ws_size,
                              hipStream_t stream) {
  const float* s   = (const float*)d_in[0];
  const float* x   = (const float*)d_in[1];
  const int*   adj = (const int*)d_in[2];
  const int*   ids = (const int*)d_in[3];
  const float* Whd = (const float*)d_in[4];
  const float* ah  = (const float*)d_in[5];
  const float* Wo  = (const float*)d_in[6];
  const float* ao  = (const float*)d_in[7];
  const float* W1  = (const float*)d_in[8];
  const float* b1  = (const float*)d_in[9];
  const float* W2  = (const float*)d_in[10];
  const float* b2  = (const float*)d_in[11];
  float* out = (float*)d_out;

  char* ws = (char*)d_ws;
  size_t off = 0;
  auto alloc = [&](size_t b) { char* p = ws + off; off += (b + 255) & ~(size_t)255; return p; };
  unsigned* mb  = (unsigned*)alloc((size_t)NN * MASKW * 4);   // 2 MB
  f16* xh       = (f16*)alloc((size_t)NN * NFEAT * 2);        // 4 MB
  f16* WcatT    = (f16*)alloc((size_t)NHH * NFEAT * 2);
  f16* WoutT    = (f16*)alloc((size_t)NHH * NHH * 2);
  f16* W1h      = (f16*)alloc((size_t)NHH * 1152 * 2);
  f16* WhT1     = (f16*)alloc((size_t)NHH * NN * 2);          // 4 MB
  f16* h1       = (f16*)alloc((size_t)NN * NHH * 2);          // 4 MB
  f16* WhT2     = (f16*)alloc((size_t)NHH * NN * 2);          // 4 MB
  f16* hcat     = (f16*)alloc((size_t)NN * 576 * 2);          // 4.5 MB
  float* sv1    = (float*)alloc((size_t)NHEADS * NN * 4);
  float* dv1    = (float*)alloc((size_t)NHEADS * NN * 4);
  float* sv2    = (float*)alloc((size_t)NN * 4);
  float* dv2    = (float*)alloc((size_t)NN * 4);
  // union region: attn partials (32.5 MB) then, after combine, Pb/Qb (16 MB)
  char* region  = alloc((size_t)JS * NN * NHH * 4 + (size_t)JS * 8 * NN * 4);
  float* pp     = (float*)region;
  float* prs    = (float*)(region + (size_t)JS * NN * NHH * 4);
  float* Pb     = (float*)region;
  float* Qb     = (float*)(region + (size_t)NN * NHH * 4);

  k_pack_mask<<<NN * MASKW / 256, 256, 0, stream>>>(adj, mb);
  k_cast<<<NN * NFEAT / 256, 256, 0, stream>>>(x, xh, NN * NFEAT);
  k_wcatT<<<NHH * NFEAT / 256, 256, 0, stream>>>(Whd, WcatT);
  k_transT<<<NHH * NHH / 256, 256, 0, stream>>>(Wo, WoutT);
  k_cast<<<NHH * 1152 / 256, 256, 0, stream>>>(W1, W1h, NHH * 1152);
  k_s_hcat<<<NN * NS / 256, 256, 0, stream>>>(s, hcat);

  // layer 1: WhT1 = (x @ Wcat)^T ; per-head src/dst ; fused attention -> h1
  k_gemm<0><<<dim3(64, 8), 256, 0, stream>>>(xh, NFEAT, WcatT, NFEAT, (void*)WhT1, NN,
                                             (const float*)nullptr, NFEAT);
  k_srcdst<<<dim3(16, 8), 256, 0, stream>>>(WhT1, ah, sv1, dv1, NHID);
  k_attn<<<dim3(64, 8, JS), 256, 0, stream>>>(WhT1, sv1, dv1, NN, mb, pp, prs);
  k_combine<true><<<NN * NHH / 256, 256, 0, stream>>>(pp, prs, h1, NHH);

  // layer 2 (out_att): WhT2 = (h1 @ W_out)^T ; attention (no ELU) -> hcat[:, :512]
  k_gemm<0><<<dim3(64, 8), 256, 0, stream>>>(h1, NHH, WoutT, NHH, (void*)WhT2, NN,
                                             (const float*)nullptr, NHH);
  k_srcdst<<<dim3(16, 1), 256, 0, stream>>>(WhT2, ao, sv2, dv2, NHH);
  k_attn<<<dim3(64, 8, JS), 256, 0, stream>>>(WhT2, sv2, dv2, 0, mb, pp, prs);
  k_combine<false><<<NN * NHH / 256, 256, 0, stream>>>(pp, prs, hcat, 576);

  // edge MLP restructure: P = hcat@W1[:, :576]^T + b1 ; Q = hcat@W1[:, 576:]^T
  k_gemm<1><<<dim3(64, 8), 256, 0, stream>>>(hcat, 576, W1h, 1152, (void*)Pb, NHH, b1, 576);
  k_gemm<1><<<dim3(64, 8), 256, 0, stream>>>(hcat, 576, W1h + 576, 1152, (void*)Qb, NHH,
                                             (const float*)nullptr, 576);
  k_edge<<<NEDGE / 4, 256, 0, stream>>>(Pb, Qb, ids, W2, b2, out);
}

// Round 10
// 718.491 us; speedup vs baseline: 1.4264x; 1.0609x over previous
//
#include <hip/hip_runtime.h>

#define NN     4096
#define NFEAT  512
#define NHID   64
#define NHEADS 8
#define NS     64
#define NEDGE  131072
#define NHH    512
#define MASKW  (NN/32)   // 128 words per row
#define JS     4         // j-split factor for attention

typedef _Float16 f16;
typedef _Float16 f16x4 __attribute__((ext_vector_type(4)));
typedef _Float16 f16x8 __attribute__((ext_vector_type(8)));
typedef float    f32x4 __attribute__((ext_vector_type(4)));

// ---------------- prep kernels ----------------

// pack adj (int32 0/1) into bitmask: bit b of word w = adj[w*32+b] > 0
__global__ __launch_bounds__(256) void k_pack_mask(const int* __restrict__ adj,
                                                   unsigned* __restrict__ mb) {
  int w = blockIdx.x * 256 + threadIdx.x;
  const int4* p = (const int4*)(adj + (size_t)w * 32);
  unsigned m = 0;
#pragma unroll
  for (int c = 0; c < 8; c++) {
    int4 v = p[c];
    m |= (v.x > 0 ? 1u : 0u) << (4*c)     | (v.y > 0 ? 1u : 0u) << (4*c + 1)
       | (v.z > 0 ? 1u : 0u) << (4*c + 2) | (v.w > 0 ? 1u : 0u) << (4*c + 3);
  }
  mb[w] = m;
}

__global__ __launch_bounds__(256) void k_cast(const float* __restrict__ in,
                                              f16* __restrict__ out, int n) {
  int i = blockIdx.x * 256 + threadIdx.x;
  if (i < n) out[i] = (f16)in[i];
}

// WcatT[n][k] = W_heads[n>>6][k][n&63]  (n = head*64+f), out [512][512] f16
__global__ __launch_bounds__(256) void k_wcatT(const float* __restrict__ W,
                                               f16* __restrict__ out) {
  int idx = blockIdx.x * 256 + threadIdx.x;
  int n = idx >> 9, k = idx & 511;
  out[idx] = (f16)W[(n >> 6) * (NFEAT * NHID) + k * NHID + (n & 63)];
}

// WoutT[n][k] = W_out[k][n]
__global__ __launch_bounds__(256) void k_transT(const float* __restrict__ W,
                                                f16* __restrict__ out) {
  int idx = blockIdx.x * 256 + threadIdx.x;
  int n = idx >> 9, k = idx & 511;
  out[idx] = (f16)W[k * NHH + n];
}

// hcat[i][512+c] = s[i][c]   (hcat leading dim 576)
__global__ __launch_bounds__(256) void k_s_hcat(const float* __restrict__ s,
                                                f16* __restrict__ hcat) {
  int idx = blockIdx.x * 256 + threadIdx.x;
  int i = idx >> 6, c = idx & 63;
  hcat[(size_t)i * 576 + 512 + c] = (f16)s[idx];
}

// ---------------- GEMM: C = A[M][lda] @ BT[n][k]^T ----------------
// MODE 0: store C^T as f16 into outT[n][ldo]   (ldo = M total)
// MODE 1: store C as f32 into out[m][ldo] (+ bias[n] if bias)
// MODE 2: store C as f16 into out[m][ldo] (+ bias[n] if bias)
// Contiguous-8 K-permutation: lane group g holds k = 8g..8g+7 (one 16B load
// per fragment). Valid since A and B share the permutation (dot is invariant).
template<int MODE>
__global__ __launch_bounds__(256) void k_gemm(const f16* __restrict__ A, int lda,
                                              const f16* __restrict__ BT, int ldbt,
                                              void* __restrict__ outp, int ldo,
                                              const float* __restrict__ bias, int K) {
  int w = threadIdx.x >> 6, l = threadIdx.x & 63;
  int g = l >> 4, ln = l & 15;
  int row  = blockIdx.x * 64 + w * 16 + ln;
  int colb = blockIdx.y * 64;
  const f16* ap = A + (size_t)row * lda + 8 * g;
  f32x4 acc[4];
#pragma unroll
  for (int nf = 0; nf < 4; nf++) acc[nf] = (f32x4){0.f, 0.f, 0.f, 0.f};
  for (int k0 = 0; k0 < K; k0 += 32) {
    f16x8 af = *(const f16x8*)(ap + k0);
#pragma unroll
    for (int nf = 0; nf < 4; nf++) {
      f16x8 bf = *(const f16x8*)(BT + (size_t)(colb + nf * 16 + ln) * ldbt + k0 + 8 * g);
      acc[nf] = __builtin_amdgcn_mfma_f32_16x16x32_f16(af, bf, acc[nf], 0, 0, 0);
    }
  }
  int m0 = blockIdx.x * 64 + w * 16 + 4 * g;   // C/D: col=lane&15, row=4*(l>>4)+r (m89)
#pragma unroll
  for (int nf = 0; nf < 4; nf++) {
    int n = colb + nf * 16 + ln;
    if (MODE == 0) {
      f16* oT = (f16*)outp;
      f16x4 v = {(f16)acc[nf][0], (f16)acc[nf][1], (f16)acc[nf][2], (f16)acc[nf][3]};
      *(f16x4*)(oT + (size_t)n * ldo + m0) = v;
    } else if (MODE == 1) {
      float* o = (float*)outp;
      float b = bias ? bias[n] : 0.f;
#pragma unroll
      for (int r = 0; r < 4; r++) o[(size_t)(m0 + r) * ldo + n] = acc[nf][r] + b;
    } else {
      f16* o = (f16*)outp;
      float b = bias ? bias[n] : 0.f;
#pragma unroll
      for (int r = 0; r < 4; r++) o[(size_t)(m0 + r) * ldo + n] = (f16)(acc[nf][r] + b);
    }
  }
}

// src[h][i] = sum_f WhT[h*fo+f][i]*a[h][f];  dst uses a[h][fo+f]
__global__ __launch_bounds__(256) void k_srcdst(const f16* __restrict__ WhT,
                                                const float* __restrict__ a,
                                                float* __restrict__ sv,
                                                float* __restrict__ dv, int fo) {
  int h = blockIdx.y;
  int i = blockIdx.x * 256 + threadIdx.x;
  const f16* wp = WhT + (size_t)h * fo * NN + i;
  const float* ap = a + h * 2 * fo;
  float sacc = 0.f, dacc = 0.f;
  for (int f = 0; f < fo; f++) {
    float v = (float)wp[(size_t)f * NN];
    sacc = fmaf(v, ap[f], sacc);
    dacc = fmaf(v, ap[fo + f], dacc);
  }
  sv[h * NN + i] = sacc;
  dv[h * NN + i] = dacc;
}

// ---------------- fused masked GAT attention (flash-style, j-split) ----------------
// grid (rowblocks=64, colblocks=8, JS). Block: 64 rows x 64 cols, j-range NN/JS.
// exp(e) needs no max-sub (|e|<~6) -> partial PV/rsum are linearly combinable.
// Writes f32 partials; k_combine normalizes. Contiguous-8 K-permutation.
// ILP: fixed trip count + unroll 2 + batched B loads; launch_bounds(,8) caps
// VGPR<=64 so 8 blocks/CU stay resident (m69 occupancy cliff at >64).
__global__ __launch_bounds__(256, 8) void k_attn(const f16* __restrict__ WhT,
                                              const float* __restrict__ sv,
                                              const float* __restrict__ dv, int sstride,
                                              const unsigned* __restrict__ mb,
                                              float* __restrict__ pp,
                                              float* __restrict__ prs) {
  int w = threadIdx.x >> 6, l = threadIdx.x & 63;
  int g = l >> 4, ln = l & 15;
  int i = blockIdx.x * 64 + w * 16 + ln;        // this lane's A-frag row
  int colbase = blockIdx.y * 64;
  int jz = blockIdx.z;
  float si = sv[blockIdx.y * sstride + i];
  const float* dp = dv + blockIdx.y * sstride + 8 * g;   // + absolute j below
  const unsigned* mrow = mb + (size_t)i * MASKW + jz * (NN / JS / 32);
  const f16* bp0 = WhT + (size_t)(colbase + ln) * NN + jz * (NN / JS) + 8 * g;
  f32x4 acc[4];
#pragma unroll
  for (int nf = 0; nf < 4; nf++) acc[nf] = (f32x4){0.f, 0.f, 0.f, 0.f};
  float rsum = 0.f;
  const int jbase = jz * (NN / JS);
#pragma unroll 2
  for (int t = 0; t < (NN / JS) / 32; ++t) {
    unsigned m32 = mrow[t];
    f32x4 dlo = *(const f32x4*)(dp + jbase + t * 32);
    f32x4 dhi = *(const f32x4*)(dp + jbase + t * 32 + 4);
    f16x8 bfr[4];
#pragma unroll
    for (int nf = 0; nf < 4; nf++)
      bfr[nf] = *(const f16x8*)(bp0 + (size_t)nf * 16 * NN + t * 32);
    f16x8 af;
#pragma unroll
    for (int d = 0; d < 4; d++) {
      float e = si + dlo[d];
      e = fmaxf(e, 0.2f * e);                    // LeakyReLU(0.2)
      float we = __expf(e);
      we = ((m32 >> (8 * g + d)) & 1u) ? we : 0.f;
      rsum += we;
      af[d] = (f16)we;
      float e2 = si + dhi[d];
      e2 = fmaxf(e2, 0.2f * e2);
      float we2 = __expf(e2);
      we2 = ((m32 >> (8 * g + 4 + d)) & 1u) ? we2 : 0.f;
      rsum += we2;
      af[4 + d] = (f16)we2;
    }
#pragma unroll
    for (int nf = 0; nf < 4; nf++)
      acc[nf] = __builtin_amdgcn_mfma_f32_16x16x32_f16(af, bfr[nf], acc[nf], 0, 0, 0);
  }
  // full row sums over this j-range: 4 lanegroups hold disjoint partials of row (l&15)
  rsum += __shfl_xor(rsum, 16, 64);
  rsum += __shfl_xor(rsum, 32, 64);
  if (l < 16)
    prs[(size_t)jz * 8 * NN + blockIdx.y * NN + blockIdx.x * 64 + w * 16 + l] = rsum;
  float* o = pp + (size_t)jz * NN * NHH;
  int m0 = blockIdx.x * 64 + w * 16 + 4 * g;
#pragma unroll
  for (int nf = 0; nf < 4; nf++)
#pragma unroll
    for (int r = 0; r < 4; r++)
      o[(size_t)(m0 + r) * NHH + colbase + nf * 16 + ln] = acc[nf][r];
}

// combine j-split partials: out[i][c] = act( sum_jz pp / sum_jz prs )
template<bool ELU>
__global__ __launch_bounds__(256) void k_combine(const float* __restrict__ pp,
                                                 const float* __restrict__ prs,
                                                 f16* __restrict__ outp, int ldo) {
  int idx = blockIdx.x * 256 + threadIdx.x;       // over NN*NHH
  int i = idx >> 9, c = idx & 511;
  float s = 0.f, rs = 0.f;
#pragma unroll
  for (int jz = 0; jz < JS; jz++) {
    s  += pp[(size_t)jz * NN * NHH + idx];
    rs += prs[(size_t)jz * 8 * NN + (size_t)(c >> 6) * NN + i];
  }
  float v = s / rs;
  if (ELU) v = v > 0.f ? v : (__expf(v) - 1.f);
  outp[(size_t)i * ldo + c] = (f16)v;
}

// ---------------- edge MLP: out[e] = dot(relu(P[src]+Q[dst]), w2) + b2 ----------------
// P, Q in f16 (halves the random-row gather bytes; 8 MB -> L2/L3 resident)
__global__ __launch_bounds__(256) void k_edge(const f16* __restrict__ P,
                                              const f16* __restrict__ Q,
                                              const int* __restrict__ ids,
                                              const float* __restrict__ w2,
                                              const float* __restrict__ b2,
                                              float* __restrict__ out) {
  int t = blockIdx.x * 256 + threadIdx.x;
  int e = t >> 6, l = t & 63;                   // one wave per edge
  int sn = ids[2 * e], dn = ids[2 * e + 1];
  f16x8 pv = *(const f16x8*)(P + (size_t)sn * NHH + l * 8);
  f16x8 qv = *(const f16x8*)(Q + (size_t)dn * NHH + l * 8);
  const float* wv = w2 + l * 8;
  f32x4 w0 = *(const f32x4*)(wv);
  f32x4 w1 = *(const f32x4*)(wv + 4);
  float acc = 0.f;
#pragma unroll
  for (int u = 0; u < 4; u++) {
    float v = (float)pv[u] + (float)qv[u];
    acc = fmaf(fmaxf(v, 0.f), w0[u], acc);
    float v2 = (float)pv[4 + u] + (float)qv[4 + u];
    acc = fmaf(fmaxf(v2, 0.f), w1[u], acc);
  }
#pragma unroll
  for (int m = 1; m < 64; m <<= 1) acc += __shfl_xor(acc, m, 64);
  if (l == 0) out[e] = acc + b2[0];
}

// ---------------- launch ----------------
extern "C" void kernel_launch(void* const* d_in, const int* in_sizes, int n_in,
                              void* d_out, int out_size, void* d_ws, size_t ws_size,
                              hipStream_t stream) {
  const float* s   = (const float*)d_in[0];
  const float* x   = (const float*)d_in[1];
  const int*   adj = (const int*)d_in[2];
  const int*   ids = (const int*)d_in[3];
  const float* Whd = (const float*)d_in[4];
  const float* ah  = (const float*)d_in[5];
  const float* Wo  = (const float*)d_in[6];
  const float* ao  = (const float*)d_in[7];
  const float* W1  = (const float*)d_in[8];
  const float* b1  = (const float*)d_in[9];
  const float* W2  = (const float*)d_in[10];
  const float* b2  = (const float*)d_in[11];
  float* out = (float*)d_out;

  char* ws = (char*)d_ws;
  size_t off = 0;
  auto alloc = [&](size_t b) { char* p = ws + off; off += (b + 255) & ~(size_t)255; return p; };
  unsigned* mb  = (unsigned*)alloc((size_t)NN * MASKW * 4);   // 2 MB
  f16* xh       = (f16*)alloc((size_t)NN * NFEAT * 2);        // 4 MB
  f16* WcatT    = (f16*)alloc((size_t)NHH * NFEAT * 2);
  f16* WoutT    = (f16*)alloc((size_t)NHH * NHH * 2);
  f16* W1h      = (f16*)alloc((size_t)NHH * 1152 * 2);
  f16* WhT1     = (f16*)alloc((size_t)NHH * NN * 2);          // 4 MB
  f16* h1       = (f16*)alloc((size_t)NN * NHH * 2);          // 4 MB
  f16* WhT2     = (f16*)alloc((size_t)NHH * NN * 2);          // 4 MB
  f16* hcat     = (f16*)alloc((size_t)NN * 576 * 2);          // 4.5 MB
  float* sv1    = (float*)alloc((size_t)NHEADS * NN * 4);
  float* dv1    = (float*)alloc((size_t)NHEADS * NN * 4);
  float* sv2    = (float*)alloc((size_t)NN * 4);
  float* dv2    = (float*)alloc((size_t)NN * 4);
  // union region: attn partials (32.5 MB) then, after combine, Pb/Qb (f16, 4 MB each)
  char* region  = alloc((size_t)JS * NN * NHH * 4 + (size_t)JS * 8 * NN * 4);
  float* pp     = (float*)region;
  float* prs    = (float*)(region + (size_t)JS * NN * NHH * 4);
  f16* Pb       = (f16*)region;
  f16* Qb       = (f16*)(region + (size_t)NN * NHH * 2);

  k_pack_mask<<<NN * MASKW / 256, 256, 0, stream>>>(adj, mb);
  k_cast<<<NN * NFEAT / 256, 256, 0, stream>>>(x, xh, NN * NFEAT);
  k_wcatT<<<NHH * NFEAT / 256, 256, 0, stream>>>(Whd, WcatT);
  k_transT<<<NHH * NHH / 256, 256, 0, stream>>>(Wo, WoutT);
  k_cast<<<NHH * 1152 / 256, 256, 0, stream>>>(W1, W1h, NHH * 1152);
  k_s_hcat<<<NN * NS / 256, 256, 0, stream>>>(s, hcat);

  // layer 1: WhT1 = (x @ Wcat)^T ; per-head src/dst ; fused attention -> h1
  k_gemm<0><<<dim3(64, 8), 256, 0, stream>>>(xh, NFEAT, WcatT, NFEAT, (void*)WhT1, NN,
                                             (const float*)nullptr, NFEAT);
  k_srcdst<<<dim3(16, 8), 256, 0, stream>>>(WhT1, ah, sv1, dv1, NHID);
  k_attn<<<dim3(64, 8, JS), 256, 0, stream>>>(WhT1, sv1, dv1, NN, mb, pp, prs);
  k_combine<true><<<NN * NHH / 256, 256, 0, stream>>>(pp, prs, h1, NHH);

  // layer 2 (out_att): WhT2 = (h1 @ W_out)^T ; attention (no ELU) -> hcat[:, :512]
  k_gemm<0><<<dim3(64, 8), 256, 0, stream>>>(h1, NHH, WoutT, NHH, (void*)WhT2, NN,
                                             (const float*)nullptr, NHH);
  k_srcdst<<<dim3(16, 1), 256, 0, stream>>>(WhT2, ao, sv2, dv2, NHH);
  k_attn<<<dim3(64, 8, JS), 256, 0, stream>>>(WhT2, sv2, dv2, 0, mb, pp, prs);
  k_combine<false><<<NN * NHH / 256, 256, 0, stream>>>(pp, prs, hcat, 576);

  // edge MLP restructure: P = hcat@W1[:, :576]^T + b1 ; Q = hcat@W1[:, 576:]^T (f16 out)
  k_gemm<2><<<dim3(64, 8), 256, 0, stream>>>(hcat, 576, W1h, 1152, (void*)Pb, NHH, b1, 576);
  k_gemm<2><<<dim3(64, 8), 256, 0, stream>>>(hcat, 576, W1h + 576, 1152, (void*)Qb, NHH,
                                             (const float*)nullptr, 576);
  k_edge<<<NEDGE / 4, 256, 0, stream>>>(Pb, Qb, ids, W2, b2, out);
}